// Round 12
// baseline (6314.198 us; speedup 1.0000x reference)
//
#include <hip/hip_runtime.h>
#include <math.h>

#define NSWEEP_MAX 16
#define T2_TOL 1e-8f    // converged when max dpq^2/(dpp*dqq) below this
#define EPS2 1e-10f     // lambda clamp 1e-5 => lambda^2 clamp 1e-10

// One-sided Jacobi on G = S (SPD). TWO 64-lane waves per matrix (128-thread
// block): wave w holds ROWS 32w..32w+31 of all 64 columns; lane l owns
// column l. Per-lane live set = g[32]+pr[32] (~70 VGPR) — rounds 5-11
// showed that the 1-wave variant's 128-float working set forced the
// allocator into AGPR staging / refetch passes (VGPR_Count stuck at
// 80-100 < 128 live), inflating issued ops ~3x. Halving per-lane state
// removes that entirely and doubles occupancy.
//
// GRAY-CODE pairing with maintained partner copy (proven round 11):
// rounds m_i = i^(i>>1); consecutive pairings differ by one bit delta, so
// re-pairing is a 1-2 op XOR-delta lane permute of pr[] (DPP quad_perm /
// row_half_mirror / row_ror:8 for bits 0-3; v_permlane16/32_swap self-swap
// for bits 4/5 — all HW-verified). pr' = cc*pr - es*g_old after each
// rotation keeps the invariant pr_l == g_{l^m} bitwise (loop-carried, not
// rematerializable).
//
// CROSS-WAVE DOT EXCHANGE: dpq = full-column dot needs both row-halves.
// Each wave computes its 32-row partial, writes it to an LDS row indexed
// by round parity (double-buffered rows 0-3 of X, free until recon), ONE
// __syncthreads(), reads the other wave's partial, and sums in FIXED
// order p_low + p_high -> bitwise identical in both waves and both lanes
// of a pair. All rotation state (dpp, pd) evolves identically in both
// waves, so the per-round skip and per-sweep break are block-uniform.
//
// TIE-SAFE rotation (proven round 5): canonical orientation
// tau = (d_hi - d_lo)*rcp(2*dpq) identical bits on both pair lanes;
// es = isLow ? -ss : +ss, t_own = isLow ? +tt : -tt.

template <int CTRL>
__device__ __forceinline__ int dpp1(int x) {
    return __builtin_amdgcn_update_dpp(0, x, CTRL, 0xF, 0xF, true);
}
template <int CTRL>
__device__ __forceinline__ float dppf1(float x) {
    return __int_as_float(dpp1<CTRL>(__float_as_int(x)));
}
__device__ __forceinline__ float swap16_self(float x) {
    asm("v_permlane16_swap_b32 %0, %0" : "+v"(x));
    return x;  // x[lane] = old x[lane^16]
}
__device__ __forceinline__ float swap32_self(float x) {
    asm("v_permlane32_swap_b32 %0, %0" : "+v"(x));
    return x;  // x[lane] = old x[lane^32]
}
__device__ __forceinline__ float rdlane_f(float x, int l) {
    return __int_as_float(__builtin_amdgcn_readlane(__float_as_int(x), l));
}

#define DPP_X1 0xB1   // quad_perm [1,0,3,2]  : lane^1
#define DPP_X2 0x4E   // quad_perm [2,3,0,1]  : lane^2
#define DPP_X3 0x1B   // quad_perm [3,2,1,0]  : lane^3
#define DPP_X7 0x141  // row_half_mirror      : lane^7
#define DPP_X8 0x128  // row_ror:8            : lane^8

__global__ __launch_bounds__(128, 2) void spdlog_onesided2(
    const float* __restrict__ S, float* __restrict__ Out, int nmat) {
    __shared__ float X[64][64];  // recon U; rows 0-5 double as exchange bufs
    const int tid = threadIdx.x;
    const int lane = tid & 63;
    const int wv = tid >> 6;      // wave id 0/1
    const int rbase = wv << 5;    // first row this wave owns
    const int b = blockIdx.x;
    if (b >= nmat) return;
    const float* Sb = S + (size_t)b * 4096;
    float* Ob = Out + (size_t)b * 4096;

    // ---- load own 32 rows of column `lane` (coalesced across lanes)
    float g[32];
    #pragma unroll 32
    for (int s = 0; s < 32; ++s) g[s] = Sb[(rbase + s) * 64 + lane];

    float dpp = 0.0f;

    #pragma unroll 1
    for (int sweep = 0; sweep < NSWEEP_MAX; ++sweep) {
        // ---- refresh Gram diagonal: own partial + other wave's partial
        {
            float d0 = 0.0f, d1 = 0.0f, d2 = 0.0f, d3 = 0.0f;
            #pragma unroll 8
            for (int s = 0; s < 32; s += 4) {
                d0 = fmaf(g[s], g[s], d0);
                d1 = fmaf(g[s + 1], g[s + 1], d1);
                d2 = fmaf(g[s + 2], g[s + 2], d2);
                d3 = fmaf(g[s + 3], g[s + 3], d3);
            }
            const float own = (d0 + d1) + (d2 + d3);
            __syncthreads();            // protect bufs from previous sweep
            X[4 + wv][lane] = own;
            __syncthreads();
            const float oth = X[4 + (1 ^ wv)][lane];
            const float p0 = wv ? oth : own;   // wave-0 (low-rows) partial
            const float p1 = wv ? own : oth;
            dpp = p0 + p1;              // fixed order: identical both waves
        }

        // ---- initial pairing m = gray(1) = 1: fetch partner copy
        float pr[32];
        #pragma unroll 32
        for (int s = 0; s < 32; ++s) pr[s] = dppf1<DPP_X1>(g[s]);
        float pd = dppf1<DPP_X1>(dpp);

        float maxt2 = 0.0f;
        #pragma unroll 1
        for (int i = 1; i < 64; ++i) {
            if (i > 1) {
                // re-pair: next partner = current ^ delta (single bit)
                const int delta = i & (-i);
                switch (delta) {
                    case 1:
                        #pragma unroll
                        for (int s = 0; s < 32; ++s) pr[s] = dppf1<DPP_X1>(pr[s]);
                        pd = dppf1<DPP_X1>(pd);
                        break;
                    case 2:
                        #pragma unroll
                        for (int s = 0; s < 32; ++s) pr[s] = dppf1<DPP_X2>(pr[s]);
                        pd = dppf1<DPP_X2>(pd);
                        break;
                    case 4:  // XOR4 = XOR3 o XOR7
                        #pragma unroll
                        for (int s = 0; s < 32; ++s)
                            pr[s] = dppf1<DPP_X7>(dppf1<DPP_X3>(pr[s]));
                        pd = dppf1<DPP_X7>(dppf1<DPP_X3>(pd));
                        break;
                    case 8:
                        #pragma unroll
                        for (int s = 0; s < 32; ++s) pr[s] = dppf1<DPP_X8>(pr[s]);
                        pd = dppf1<DPP_X8>(pd);
                        break;
                    case 16:
                        #pragma unroll
                        for (int s = 0; s < 32; ++s) pr[s] = swap16_self(pr[s]);
                        pd = swap16_self(pd);
                        break;
                    default:  // 32
                        #pragma unroll
                        for (int s = 0; s < 32; ++s) pr[s] = swap32_self(pr[s]);
                        pd = swap32_self(pd);
                        break;
                }
            }
            const int m = i ^ (i >> 1);
            const int xl = lane ^ m;
            const bool isLow = lane < xl;
            // ---- own-rows partial of the Gram cross term (pair-symmetric:
            // fma(a,b,c)==fma(b,a,c) bitwise, same order on both pair lanes)
            float a0 = 0.0f, a1 = 0.0f, a2 = 0.0f, a3 = 0.0f;
            #pragma unroll 8
            for (int s = 0; s < 32; s += 4) {
                a0 = fmaf(g[s], pr[s], a0);
                a1 = fmaf(g[s + 1], pr[s + 1], a1);
                a2 = fmaf(g[s + 2], pr[s + 2], a2);
                a3 = fmaf(g[s + 3], pr[s + 3], a3);
            }
            const float own = (a0 + a1) + (a2 + a3);
            // ---- cross-wave exchange (parity double-buffer, 1 barrier)
            const int pbuf = (i & 1) << 1;
            X[pbuf + wv][lane] = own;
            __syncthreads();
            const float oth = X[pbuf + (1 ^ wv)][lane];
            const float p0 = wv ? oth : own;
            const float p1 = wv ? own : oth;
            const float dpq = p0 + p1;  // fixed order: identical both waves
            const float t2 = dpq * dpq * __builtin_amdgcn_rcpf(dpp * pd);
            maxt2 = fmaxf(maxt2, t2);
            // block-uniform skip (t2 bitwise identical across waves)
            if (__all(t2 < T2_TOL)) continue;
            // ---- canonical rotation (identical bits on both pair lanes)
            const float d_lo = isLow ? dpp : pd;
            const float d_hi = isLow ? pd : dpp;
            const float tau = (d_hi - d_lo) * __builtin_amdgcn_rcpf(2.0f * dpq);
            const float sq = __builtin_amdgcn_sqrtf(fmaf(tau, tau, 1.0f));
            float tt = __builtin_amdgcn_rcpf(fabsf(tau) + sq);
            tt = copysignf(tt, tau);
            float cc = __builtin_amdgcn_rsqf(fmaf(tt, tt, 1.0f));
            float ss = tt * cc;
            const bool tiny = fabsf(dpq) < 1e-30f;
            cc = tiny ? 1.0f : cc;
            ss = tiny ? 0.0f : ss;
            tt = tiny ? 0.0f : tt;
            const float es = isLow ? -ss : ss;
            const float t_own = isLow ? tt : -tt;
            const float pdn = fmaf(t_own, dpq, pd);
            dpp = fmaf(-t_own, dpq, dpp);
            pd = pdn;
            // ---- rotate own rows AND maintain partner copy (bitwise
            // mirror of the partner's own update)
            #pragma unroll 32
            for (int s = 0; s < 32; ++s) {
                const float m1 = es * pr[s];
                const float m2 = es * g[s];
                g[s] = fmaf(cc, g[s], m1);
                pr[s] = fmaf(cc, pr[s], -m2);
            }
        }
        // ---- wave max of maxt2 (same value in both waves)
        maxt2 = fmaxf(maxt2, __shfl_xor(maxt2, 1));
        maxt2 = fmaxf(maxt2, __shfl_xor(maxt2, 2));
        maxt2 = fmaxf(maxt2, __shfl_xor(maxt2, 4));
        maxt2 = fmaxf(maxt2, __shfl_xor(maxt2, 8));
        maxt2 = fmaxf(maxt2, __shfl_xor(maxt2, 16));
        maxt2 = fmaxf(maxt2, __shfl_xor(maxt2, 32));
        if (maxt2 < T2_TOL) break;  // block-uniform
    }

    // ---- final column norm^2 (cross-wave), eigenvalue, normalize
    float dfin;
    {
        float d0 = 0.0f, d1 = 0.0f;
        #pragma unroll 16
        for (int s = 0; s < 32; s += 2) {
            d0 = fmaf(g[s], g[s], d0);
            d1 = fmaf(g[s + 1], g[s + 1], d1);
        }
        const float own = d0 + d1;
        __syncthreads();
        X[4 + wv][lane] = own;
        __syncthreads();
        const float oth = X[4 + (1 ^ wv)][lane];
        const float p0 = wv ? oth : own;
        const float p1 = wv ? own : oth;
        dfin = p0 + p1;
    }
    const float w = 0.5f * logf(fmaxf(dfin, EPS2));
    const float rs = __builtin_amdgcn_rsqf(fmaxf(dfin, 1e-20f));

    // ---- store U rows (own half) into X, then O = U diag(w) U^T
    __syncthreads();  // exchange reads done before overwriting rows 4/5
    #pragma unroll 32
    for (int s = 0; s < 32; ++s) X[rbase + s][lane] = g[s] * rs;
    __syncthreads();
    float uw[64];
    {
        const float4* rowp = (const float4*)&X[lane][0];  // own row of U
        #pragma unroll 16
        for (int gq = 0; gq < 16; ++gq) {
            const float4 q = rowp[gq];
            uw[4 * gq + 0] = q.x;
            uw[4 * gq + 1] = q.y;
            uw[4 * gq + 2] = q.z;
            uw[4 * gq + 3] = q.w;
        }
    }
    #pragma unroll 64
    for (int c = 0; c < 64; ++c) uw[c] *= rdlane_f(w, c);
    // each wave emits its own 32 output rows
    #pragma unroll 2
    for (int ii = 0; ii < 32; ++ii) {
        const int i = rbase + ii;
        const float4* Urow = (const float4*)&X[i][0];  // wave-uniform: bcast
        float acc = 0.0f;
        #pragma unroll 16
        for (int gq = 0; gq < 16; ++gq) {
            const float4 q = Urow[gq];
            acc = fmaf(q.x, uw[4 * gq + 0], acc);
            acc = fmaf(q.y, uw[4 * gq + 1], acc);
            acc = fmaf(q.z, uw[4 * gq + 2], acc);
            acc = fmaf(q.w, uw[4 * gq + 3], acc);
        }
        Ob[i * 64 + lane] = acc;
    }
}

extern "C" void kernel_launch(void* const* d_in, const int* in_sizes, int n_in,
                              void* d_out, int out_size, void* d_ws, size_t ws_size,
                              hipStream_t stream) {
    const float* S = (const float*)d_in[0];
    float* Out = (float*)d_out;
    const int nmat = in_sizes[0] / 4096;
    spdlog_onesided2<<<nmat, 128, 0, stream>>>(S, Out, nmat);
}